// Round 9
// baseline (304.742 us; speedup 1.0000x reference)
//
#include <hip/hip_runtime.h>
#include <math.h>

#define N_NODES 100000
#define N_EDGES 3200000
#define F_IN    512
#define H1      16
#define H2      40

#define NB      391      // coarse buckets: dst >> 8, 256 nodes each
#define BSH     8
#define BMASK   255
#define B1      512      // phase-1/2 blocks
#define EPB     6250     // edges per block (512*6250 = 3.2M exactly)

// ---------------------------------------------------------------------------
// Detect edge_index dtype: int64 (high int32 words all zero) vs int32.
__global__ void detect_idx_kernel(const int* __restrict__ ei, int* __restrict__ flag)
{
    if (threadIdx.x == 0 && blockIdx.x == 0) {
        int all_zero = 1;
        for (int i = 0; i < 64; ++i)
            if (ei[2 * i + 1] != 0) { all_zero = 0; break; }
        *flag = all_zero;  // 1 => int64 layout, 0 => int32 layout
    }
}

__device__ __forceinline__ int edge_src(const void* ei, int e, int is64)
{
    return is64 ? (int)((const long long*)ei)[e] : ((const int*)ei)[e];
}
__device__ __forceinline__ int edge_dst(const void* ei, int e, int is64)
{
    return is64 ? (int)((const long long*)ei)[N_EDGES + e]
                : ((const int*)ei)[N_EDGES + e];
}

// ---------------------------------------------------------------------------
// Phase 1: per-block coarse-bucket histogram (LDS atomics only).
__global__ __launch_bounds__(256) void hist_kernel(
    const void* __restrict__ ei, const int* __restrict__ flag,
    int* __restrict__ cntoff)
{
    __shared__ int h[NB];
    for (int i = threadIdx.x; i < NB; i += 256) h[i] = 0;
    __syncthreads();
    const int is64 = *flag;
    const int e0 = blockIdx.x * EPB;
    for (int i = threadIdx.x; i < EPB; i += 256) {
        int e = e0 + i;
        if (e < N_EDGES) atomicAdd(&h[edge_dst(ei, e, is64) >> BSH], 1);
    }
    __syncthreads();
    for (int i = threadIdx.x; i < NB; i += 256)
        cntoff[blockIdx.x * NB + i] = h[i];
}

// ---------------------------------------------------------------------------
// Phase 1b: per-bucket exclusive scan over the 512 blocks (one wave/bucket).
__global__ __launch_bounds__(256) void scanblk_kernel(
    int* __restrict__ cntoff, int* __restrict__ bstart)
{
    const int lane   = threadIdx.x & 63;
    const int bucket = blockIdx.x * 4 + (threadIdx.x >> 6);
    if (bucket >= NB) return;
    int run = 0;
    #pragma unroll
    for (int c = 0; c < B1 / 64; ++c) {
        const int i = c * 64 + lane;
        const int v = cntoff[i * NB + bucket];
        int s = v;
        #pragma unroll
        for (int off = 1; off < 64; off <<= 1) {
            int t = __shfl_up(s, off, 64);
            if (lane >= off) s += t;
        }
        cntoff[i * NB + bucket] = run + (s - v);   // exclusive within bucket
        run += __shfl(s, 63, 64);
    }
    if (lane == 0) bstart[bucket] = run;
}

// Phase 1c: exclusive scan of the NB bucket totals.
__global__ __launch_bounds__(512) void scanb_kernel(int* __restrict__ bstart)
{
    __shared__ int s[512];
    const int t = threadIdx.x;
    const int v = (t < NB) ? bstart[t] : 0;
    s[t] = v;
    __syncthreads();
    for (int off = 1; off < 512; off <<= 1) {
        int tv = (t >= off) ? s[t - off] : 0;
        __syncthreads();
        s[t] += tv;
        __syncthreads();
    }
    if (t < NB) bstart[t] = s[t] - v;              // exclusive
    if (t == NB - 1) bstart[NB] = s[t];            // total == N_EDGES
}

// ---------------------------------------------------------------------------
// Phase 2: scatter edges into bucket-sorted packed array (LDS cursors only).
// packed = (src << 8) | (dst & 255); src < 2^17 fits easily.
__global__ __launch_bounds__(256) void scatter_bucket_kernel(
    const void* __restrict__ ei, const int* __restrict__ flag,
    const int* __restrict__ cntoff, const int* __restrict__ bstart,
    int* __restrict__ packed)
{
    __shared__ int cur[NB];
    for (int i = threadIdx.x; i < NB; i += 256)
        cur[i] = cntoff[blockIdx.x * NB + i] + bstart[i];
    __syncthreads();
    const int is64 = *flag;
    const int e0 = blockIdx.x * EPB;
    for (int i = threadIdx.x; i < EPB; i += 256) {
        int e = e0 + i;
        if (e >= N_EDGES) break;
        const int s = edge_src(ei, e, is64);
        const int d = edge_dst(ei, e, is64);
        const int b = d >> BSH;
        const int pos = atomicAdd(&cur[b], 1);
        packed[pos] = (s << BSH) | (d & BMASK);
    }
}

// ---------------------------------------------------------------------------
// Phase 3: one block per bucket (256 nodes); fine CSR via LDS hist+scan+scatter.
// row_end[g] = inclusive global prefix; beg(g) = row_end[g-1].
__global__ __launch_bounds__(512) void bucket_csr_kernel(
    const int* __restrict__ packed, const int* __restrict__ bstart,
    int* __restrict__ deg, int* __restrict__ row_end, int* __restrict__ csr)
{
    __shared__ int hist[256];
    __shared__ int off[256];
    const int b    = blockIdx.x;
    const int tid  = threadIdx.x;
    const int base = bstart[b];
    const int m    = bstart[b + 1] - base;

    if (tid < 256) hist[tid] = 0;
    __syncthreads();
    for (int i = tid; i < m; i += 512)
        atomicAdd(&hist[packed[base + i] & BMASK], 1);
    __syncthreads();

    int v = 0;
    if (tid < 256) { v = hist[tid]; off[tid] = v; }
    __syncthreads();
    for (int o = 1; o < 256; o <<= 1) {
        int t2 = 0;
        if (tid < 256 && tid >= o) t2 = off[tid - o];
        __syncthreads();
        if (tid < 256) off[tid] += t2;
        __syncthreads();
    }
    if (tid < 256) {
        const int g = (b << BSH) + tid;
        if (g < N_NODES) { deg[g] = v; row_end[g] = base + off[tid]; }
        off[tid] -= v;                              // exclusive, reuse as cursor
    }
    __syncthreads();
    for (int i = tid; i < m; i += 512) {
        const int p = packed[base + i];
        const int pos = atomicAdd(&off[p & BMASK], 1);
        csr[base + pos] = p >> BSH;
    }
}

// ---------------------------------------------------------------------------
// Split-K GEMM1: partial[h][r][j] = sum_{k in half h} x[r][k]*W1[k][j].
// Little's law: thread-per-row full-K gives only N/64=1563 waves = 6.1/CU,
// far too few outstanding x-line fetches (need ~50-70/CU at ~900cy latency).
// Split-K x2 -> 12.2 waves/CU; each thread consumes its 128B lines in
// unroll-8 groups (full line per group). W1 read at wave-uniform addresses.
__global__ __launch_bounds__(256) void gemm1_kernel(
    const float* __restrict__ x, const float* __restrict__ W1,
    float* __restrict__ partial, int n)
{
    const int rb = blockIdx.x >> 1;                 // row-block
    const int h  = blockIdx.x & 1;                  // k-half
    const int r  = rb * 256 + threadIdx.x;
    if (r >= n) return;

    const float4* xr = (const float4*)(x + (size_t)r * F_IN) + h * 64;
    const float*  Wb = W1 + h * (F_IN / 2) * H1;

    float acc[H1];
    #pragma unroll
    for (int j = 0; j < H1; ++j) acc[j] = 0.f;

    #pragma unroll 8
    for (int k4 = 0; k4 < 64; ++k4) {
        const float4 xv = xr[k4];
        const float* wk = Wb + k4 * 4 * H1;         // wave-uniform address
        #pragma unroll
        for (int j = 0; j < H1; ++j)
            acc[j] += xv.x * wk[j] + xv.y * wk[H1 + j]
                    + xv.z * wk[2 * H1 + j] + xv.w * wk[3 * H1 + j];
    }

    float4* o = (float4*)(partial + (size_t)h * N_NODES * H1 + (size_t)r * H1);
    #pragma unroll
    for (int q = 0; q < 4; ++q) {
        float4 v;
        v.x = acc[4 * q + 0]; v.y = acc[4 * q + 1];
        v.z = acc[4 * q + 2]; v.w = acc[4 * q + 3];
        o[q] = v;
    }
}

// ---------------------------------------------------------------------------
// Combine: hs1[r] = (partial[0][r] + partial[1][r]) * dis[r]; dis = rsqrt(deg+1).
// hs1 aliases partial[0]; elementwise in-place is safe.
__global__ __launch_bounds__(256) void combine_kernel(
    float* __restrict__ partial, const int* __restrict__ deg,
    float* __restrict__ dis, int n)
{
    int t = blockIdx.x * 256 + threadIdx.x;
    int g = t >> 2;
    int q = t & 3;
    if (g >= n) return;
    float4 a = ((const float4*)(partial + (size_t)g * H1))[q];
    float4 b = ((const float4*)(partial + (size_t)N_NODES * H1 + (size_t)g * H1))[q];
    const float dv = rsqrtf((float)deg[g] + 1.0f);
    if (q == 0) dis[g] = dv;
    float4 o;
    o.x = (a.x + b.x) * dv; o.y = (a.y + b.y) * dv;
    o.z = (a.z + b.z) * dv; o.w = (a.w + b.w) * dv;
    ((float4*)(partial + (size_t)g * H1))[q] = o;
}

// ---------------------------------------------------------------------------
// Pull aggregation over 16-dim rows: 4-lane group per node, float4 per lane.
// FUSE_L1: c = dis * relu(dis*(acc + hs1_self) + b1) (layer-1 epilogue)
template <int FUSE_L1>
__global__ __launch_bounds__(256) void pull16_kernel(
    const int* __restrict__ row_end, const int* __restrict__ csr,
    const float* __restrict__ rows, const float* __restrict__ dis,
    const float* __restrict__ b1, float* __restrict__ out, int n)
{
    int t = blockIdx.x * 256 + threadIdx.x;
    int g = t >> 2;
    int q = t & 3;
    if (g >= n) return;
    int beg = (g == 0) ? 0 : row_end[g - 1];
    int end = row_end[g];
    float4 acc = make_float4(0.f, 0.f, 0.f, 0.f);
    for (int i = beg; i < end; ++i) {
        int s = csr[i];
        float4 v = ((const float4*)(rows + (size_t)s * H1))[q];
        acc.x += v.x; acc.y += v.y; acc.z += v.z; acc.w += v.w;
    }
    if (FUSE_L1) {
        const float dv = dis[g];
        float4 h = ((const float4*)(rows + (size_t)g * H1))[q];  // self-loop
        float4 bq = ((const float4*)b1)[q];
        acc.x = dv * fmaxf(dv * (acc.x + h.x) + bq.x, 0.f);
        acc.y = dv * fmaxf(dv * (acc.y + h.y) + bq.y, 0.f);
        acc.z = dv * fmaxf(dv * (acc.z + h.z) + bq.z, 0.f);
        acc.w = dv * fmaxf(dv * (acc.w + h.w) + bq.w, 0.f);
    }
    ((float4*)(out + (size_t)g * H1))[q] = acc;
}

// ---------------------------------------------------------------------------
// out[r][j] = log_softmax_j( dis[r] * ((agg2[r]+c[r]) @ W2)[j] + b2[j] )
__global__ __launch_bounds__(256) void epi_kernel(
    const float* __restrict__ agg2, const float* __restrict__ c,
    const float* __restrict__ W2, const float* __restrict__ b2,
    const float* __restrict__ dis, float* __restrict__ out, int n)
{
    __shared__ float w[H1 * H2];
    for (int t = threadIdx.x; t < H1 * H2; t += 256) w[t] = W2[t];
    __syncthreads();

    const int row  = blockIdx.x * 4 + (threadIdx.x >> 6);
    if (row >= n) return;
    const int lane = threadIdx.x & 63;

    float tv = 0.f;
    if (lane < H1)
        tv = agg2[(size_t)row * H1 + lane] + c[(size_t)row * H1 + lane];

    const float dv = dis[row];
    float val = -INFINITY;
    if (lane < H2) {
        float s = 0.f;
        #pragma unroll
        for (int k = 0; k < H1; ++k) {
            float tk = __shfl(tv, k, 64);
            s += tk * w[k * H2 + lane];
        }
        val = dv * s + b2[lane];
    }
    float m = val;
    #pragma unroll
    for (int off = 32; off > 0; off >>= 1) m = fmaxf(m, __shfl_xor(m, off, 64));
    float ex = (lane < H2) ? __expf(val - m) : 0.f;
    #pragma unroll
    for (int off = 32; off > 0; off >>= 1) ex += __shfl_xor(ex, off, 64);
    if (lane < H2) out[(size_t)row * H2 + lane] = val - m - logf(ex);
}

// ---------------------------------------------------------------------------
extern "C" void kernel_launch(void* const* d_in, const int* in_sizes, int n_in,
                              void* d_out, int out_size, void* d_ws, size_t ws_size,
                              hipStream_t stream)
{
    const float* x   = (const float*)d_in[0];
    const void*  ei  = d_in[1];                 // int32 or int64 [2, E] — detected
    const float* W1  = (const float*)d_in[2];
    const float* b1  = (const float*)d_in[3];
    const float* W2  = (const float*)d_in[4];
    const float* b2  = (const float*)d_in[5];
    float*       out = (float*)d_out;

    // workspace layout (4-byte units); ~27.6 MB total, float4-aligned slabs.
    // REGION (E ints = 12.8MB) is time-multiplexed:
    //   CSR build:  packed
    //   gemm1:      partial[2][N][16]  (2 x 6.4MB = 12.8MB exactly)
    //   pulls:      hs1 = partial[0], c = partial[1]
    int*   base    = (int*)d_ws;
    int*   flag    = base;                                  // 16
    int*   deg     = base + 16;                             // N
    int*   row_end = deg + N_NODES;                         // N
    int*   bstart  = row_end + N_NODES;                     // 512 (NB+1 used)
    int*   cntoff  = bstart + 512;                          // B1*NB = 200192
    float* dis     = (float*)(cntoff + B1 * NB);            // N
    int*   csr     = (int*)(dis + N_NODES);                 // E
    int*   REGION  = csr + N_EDGES;                         // E
    int*   packed  = REGION;
    float* partial = (float*)REGION;                        // [2][N][16]
    float* hs1     = partial;                               // alias partial[0]
    float* c       = hs1 + (size_t)N_NODES * H1;            // alias partial[1]
    float* agg2    = hs1;                                   // hs1 dead after pull1

    detect_idx_kernel<<<1, 64, 0, stream>>>((const int*)ei, flag);

    hist_kernel<<<B1, 256, 0, stream>>>(ei, flag, cntoff);
    scanblk_kernel<<<(NB + 3) / 4, 256, 0, stream>>>(cntoff, bstart);
    scanb_kernel<<<1, 512, 0, stream>>>(bstart);
    scatter_bucket_kernel<<<B1, 256, 0, stream>>>(ei, flag, cntoff, bstart, packed);
    bucket_csr_kernel<<<NB, 512, 0, stream>>>(packed, bstart, deg, row_end, csr);

    const int RB = (N_NODES + 255) / 256;        // 391 row-blocks per half
    gemm1_kernel<<<2 * RB, 256, 0, stream>>>(x, W1, partial, N_NODES);

    const int PB = (N_NODES * 4 + 255) / 256;
    combine_kernel<<<PB, 256, 0, stream>>>(partial, deg, dis, N_NODES);

    pull16_kernel<1><<<PB, 256, 0, stream>>>(row_end, csr, hs1, dis, b1, c, N_NODES);
    pull16_kernel<0><<<PB, 256, 0, stream>>>(row_end, csr, c, dis, b1, agg2, N_NODES);

    epi_kernel<<<(N_NODES + 3) / 4, 256, 0, stream>>>(agg2, c, W2, b2, dis, out, N_NODES);
}

// Round 10
// 298.000 us; speedup vs baseline: 1.0226x; 1.0226x over previous
//
#include <hip/hip_runtime.h>
#include <math.h>

#define N_NODES 100000
#define N_EDGES 3200000
#define F_IN    512
#define H1      16
#define H2      40

#define NB      391      // coarse buckets: dst >> 8, 256 nodes each
#define BSH     8
#define BMASK   255
#define B1      512      // phase-1/2 blocks
#define EPB     6250     // edges per block (512*6250 = 3.2M exactly)

#define GROWS   256      // gemm1 rows per block
#define KT      32       // gemm1 k-floats per tile
#define NKT     (F_IN / KT)

// ---------------------------------------------------------------------------
// Detect edge_index dtype: int64 (high int32 words all zero) vs int32.
__global__ void detect_idx_kernel(const int* __restrict__ ei, int* __restrict__ flag)
{
    if (threadIdx.x == 0 && blockIdx.x == 0) {
        int all_zero = 1;
        for (int i = 0; i < 64; ++i)
            if (ei[2 * i + 1] != 0) { all_zero = 0; break; }
        *flag = all_zero;  // 1 => int64 layout, 0 => int32 layout
    }
}

__device__ __forceinline__ int edge_src(const void* ei, int e, int is64)
{
    return is64 ? (int)((const long long*)ei)[e] : ((const int*)ei)[e];
}
__device__ __forceinline__ int edge_dst(const void* ei, int e, int is64)
{
    return is64 ? (int)((const long long*)ei)[N_EDGES + e]
                : ((const int*)ei)[N_EDGES + e];
}

// ---------------------------------------------------------------------------
// Phase 1: per-block coarse-bucket histogram (LDS atomics only).
__global__ __launch_bounds__(256) void hist_kernel(
    const void* __restrict__ ei, const int* __restrict__ flag,
    int* __restrict__ cntoff)
{
    __shared__ int h[NB];
    for (int i = threadIdx.x; i < NB; i += 256) h[i] = 0;
    __syncthreads();
    const int is64 = *flag;
    const int e0 = blockIdx.x * EPB;
    for (int i = threadIdx.x; i < EPB; i += 256) {
        int e = e0 + i;
        if (e < N_EDGES) atomicAdd(&h[edge_dst(ei, e, is64) >> BSH], 1);
    }
    __syncthreads();
    for (int i = threadIdx.x; i < NB; i += 256)
        cntoff[blockIdx.x * NB + i] = h[i];
}

// ---------------------------------------------------------------------------
// Phase 1b: per-bucket exclusive scan over the 512 blocks (one wave/bucket).
__global__ __launch_bounds__(256) void scanblk_kernel(
    int* __restrict__ cntoff, int* __restrict__ bstart)
{
    const int lane   = threadIdx.x & 63;
    const int bucket = blockIdx.x * 4 + (threadIdx.x >> 6);
    if (bucket >= NB) return;
    int run = 0;
    #pragma unroll
    for (int c = 0; c < B1 / 64; ++c) {
        const int i = c * 64 + lane;
        const int v = cntoff[i * NB + bucket];
        int s = v;
        #pragma unroll
        for (int off = 1; off < 64; off <<= 1) {
            int t = __shfl_up(s, off, 64);
            if (lane >= off) s += t;
        }
        cntoff[i * NB + bucket] = run + (s - v);   // exclusive within bucket
        run += __shfl(s, 63, 64);
    }
    if (lane == 0) bstart[bucket] = run;
}

// Phase 1c: exclusive scan of the NB bucket totals.
__global__ __launch_bounds__(512) void scanb_kernel(int* __restrict__ bstart)
{
    __shared__ int s[512];
    const int t = threadIdx.x;
    const int v = (t < NB) ? bstart[t] : 0;
    s[t] = v;
    __syncthreads();
    for (int off = 1; off < 512; off <<= 1) {
        int tv = (t >= off) ? s[t - off] : 0;
        __syncthreads();
        s[t] += tv;
        __syncthreads();
    }
    if (t < NB) bstart[t] = s[t] - v;              // exclusive
    if (t == NB - 1) bstart[NB] = s[t];            // total == N_EDGES
}

// ---------------------------------------------------------------------------
// Phase 2: scatter edges into bucket-sorted packed array (LDS cursors only).
__global__ __launch_bounds__(256) void scatter_bucket_kernel(
    const void* __restrict__ ei, const int* __restrict__ flag,
    const int* __restrict__ cntoff, const int* __restrict__ bstart,
    int* __restrict__ packed)
{
    __shared__ int cur[NB];
    for (int i = threadIdx.x; i < NB; i += 256)
        cur[i] = cntoff[blockIdx.x * NB + i] + bstart[i];
    __syncthreads();
    const int is64 = *flag;
    const int e0 = blockIdx.x * EPB;
    for (int i = threadIdx.x; i < EPB; i += 256) {
        int e = e0 + i;
        if (e >= N_EDGES) break;
        const int s = edge_src(ei, e, is64);
        const int d = edge_dst(ei, e, is64);
        const int b = d >> BSH;
        const int pos = atomicAdd(&cur[b], 1);
        packed[pos] = (s << BSH) | (d & BMASK);
    }
}

// ---------------------------------------------------------------------------
// Phase 3: one block per bucket (256 nodes); fine CSR via LDS hist+scan+scatter.
__global__ __launch_bounds__(512) void bucket_csr_kernel(
    const int* __restrict__ packed, const int* __restrict__ bstart,
    int* __restrict__ deg, int* __restrict__ row_end, int* __restrict__ csr)
{
    __shared__ int hist[256];
    __shared__ int off[256];
    const int b    = blockIdx.x;
    const int tid  = threadIdx.x;
    const int base = bstart[b];
    const int m    = bstart[b + 1] - base;

    if (tid < 256) hist[tid] = 0;
    __syncthreads();
    for (int i = tid; i < m; i += 512)
        atomicAdd(&hist[packed[base + i] & BMASK], 1);
    __syncthreads();

    int v = 0;
    if (tid < 256) { v = hist[tid]; off[tid] = v; }
    __syncthreads();
    for (int o = 1; o < 256; o <<= 1) {
        int t2 = 0;
        if (tid < 256 && tid >= o) t2 = off[tid - o];
        __syncthreads();
        if (tid < 256) off[tid] += t2;
        __syncthreads();
    }
    if (tid < 256) {
        const int g = (b << BSH) + tid;
        if (g < N_NODES) { deg[g] = v; row_end[g] = base + off[tid]; }
        off[tid] -= v;                              // exclusive, reuse as cursor
    }
    __syncthreads();
    for (int i = tid; i < m; i += 512) {
        const int p = packed[base + i];
        const int pos = atomicAdd(&off[p & BMASK], 1);
        csr[base + pos] = p >> BSH;
    }
}

// ---------------------------------------------------------------------------
// GEMM1 via global_load_lds staging (fire-and-forget: compiler cannot
// serialize it into load-use chains — the round-7/8/9 failure mode).
// Block = 256 rows; K tiled x16 (32 floats/row/tile = 32KB tile), double
// buffered (64KB LDS, 2 blocks/CU). Per tile each wave issues 8
// global_load_lds_dwordx4; each instruction covers 8 whole 128B lines
// (8 lanes x 16B per row, rows 8-aligned) -> ~64 lines in flight/wave.
// Counted vmcnt(8) + raw s_barrier keeps next-tile loads in flight
// across the barrier (T3/T4). LDS XOR swizzle both sides (rule #21):
// source chunk = (lane&7) ^ ((lane>>3)&7); read slot = c ^ (row&7)
// -> conflict-free ds_read_b128 (linear would be 32-way).
__global__ __launch_bounds__(256) void gemm1_kernel(
    const float* __restrict__ x, const float* __restrict__ W1,
    const int* __restrict__ deg, float* __restrict__ hs1,
    float* __restrict__ dis, int n)
{
    __shared__ __attribute__((aligned(16))) float lds[2][GROWS * KT];

    const int tid  = threadIdx.x;
    const int wave = tid >> 6;
    const int lane = tid & 63;
    const int r0   = blockIdx.x * GROWS;

    const int lrow  = lane >> 3;          // row-in-8-group
    const int lslot = lane & 7;           // 16B slot within row's 128B
    const int lchunk = lslot ^ lrow;      // swizzled global chunk (row&7 == lrow)

    // issue one tile's 8 glds for this wave
    auto issue = [&](int kt, int buf) {
        #pragma unroll
        for (int ii = 0; ii < 8; ++ii) {
            int row_g = r0 + wave * 64 + ii * 8 + lrow;
            if (row_g > n - 1) row_g = n - 1;          // clamp (last block)
            const float* g = x + (size_t)row_g * F_IN + kt * KT + lchunk * 4;
            float* l = &lds[buf][(wave * 8 + ii) * 256];   // 1KB per instr
            __builtin_amdgcn_global_load_lds(
                (const __attribute__((address_space(1))) void*)g,
                (__attribute__((address_space(3))) void*)l,
                16, 0, 0);
        }
    };

    float acc[H1];
    #pragma unroll
    for (int j = 0; j < H1; ++j) acc[j] = 0.f;

    issue(0, 0);

    for (int kt = 0; kt < NKT; ++kt) {
        const int buf = kt & 1;
        if (kt + 1 < NKT) {
            issue(kt + 1, buf ^ 1);
            asm volatile("s_waitcnt vmcnt(8)" ::: "memory");  // tile kt landed
        } else {
            asm volatile("s_waitcnt vmcnt(0)" ::: "memory");
        }
        __builtin_amdgcn_s_barrier();          // raw: no vmcnt(0) drain
        __builtin_amdgcn_sched_barrier(0);
        #pragma unroll
        for (int c = 0; c < 8; ++c) {
            const float4 xv =
                *(const float4*)&lds[buf][tid * KT + ((c ^ (tid & 7)) << 2)];
            const float* wk = W1 + (kt * KT + c * 4) * H1;  // wave-uniform
            #pragma unroll
            for (int j = 0; j < H1; ++j) {
                acc[j] = fmaf(xv.x, wk[j],          acc[j]);
                acc[j] = fmaf(xv.y, wk[H1 + j],     acc[j]);
                acc[j] = fmaf(xv.z, wk[2 * H1 + j], acc[j]);
                acc[j] = fmaf(xv.w, wk[3 * H1 + j], acc[j]);
            }
        }
        __builtin_amdgcn_s_barrier();          // protect buf before reissue
    }

    const int r = r0 + tid;
    if (r < n) {
        const float dv = rsqrtf((float)deg[r] + 1.0f);
        dis[r] = dv;
        float4* o = (float4*)(hs1 + (size_t)r * H1);
        #pragma unroll
        for (int q = 0; q < 4; ++q) {
            float4 v;
            v.x = acc[4 * q + 0] * dv;
            v.y = acc[4 * q + 1] * dv;
            v.z = acc[4 * q + 2] * dv;
            v.w = acc[4 * q + 3] * dv;
            o[q] = v;
        }
    }
}

// ---------------------------------------------------------------------------
// Pull aggregation over 16-dim rows: 4-lane group per node, float4 per lane.
// FUSE_L1: c = dis * relu(dis*(acc + hs1_self) + b1) (layer-1 epilogue)
template <int FUSE_L1>
__global__ __launch_bounds__(256) void pull16_kernel(
    const int* __restrict__ row_end, const int* __restrict__ csr,
    const float* __restrict__ rows, const float* __restrict__ dis,
    const float* __restrict__ b1, float* __restrict__ out, int n)
{
    int t = blockIdx.x * 256 + threadIdx.x;
    int g = t >> 2;
    int q = t & 3;
    if (g >= n) return;
    int beg = (g == 0) ? 0 : row_end[g - 1];
    int end = row_end[g];
    float4 acc = make_float4(0.f, 0.f, 0.f, 0.f);
    for (int i = beg; i < end; ++i) {
        int s = csr[i];
        float4 v = ((const float4*)(rows + (size_t)s * H1))[q];
        acc.x += v.x; acc.y += v.y; acc.z += v.z; acc.w += v.w;
    }
    if (FUSE_L1) {
        const float dv = dis[g];
        float4 h = ((const float4*)(rows + (size_t)g * H1))[q];  // self-loop
        float4 bq = ((const float4*)b1)[q];
        acc.x = dv * fmaxf(dv * (acc.x + h.x) + bq.x, 0.f);
        acc.y = dv * fmaxf(dv * (acc.y + h.y) + bq.y, 0.f);
        acc.z = dv * fmaxf(dv * (acc.z + h.z) + bq.z, 0.f);
        acc.w = dv * fmaxf(dv * (acc.w + h.w) + bq.w, 0.f);
    }
    ((float4*)(out + (size_t)g * H1))[q] = acc;
}

// ---------------------------------------------------------------------------
// out[r][j] = log_softmax_j( dis[r] * ((agg2[r]+c[r]) @ W2)[j] + b2[j] )
__global__ __launch_bounds__(256) void epi_kernel(
    const float* __restrict__ agg2, const float* __restrict__ c,
    const float* __restrict__ W2, const float* __restrict__ b2,
    const float* __restrict__ dis, float* __restrict__ out, int n)
{
    __shared__ float w[H1 * H2];
    for (int t = threadIdx.x; t < H1 * H2; t += 256) w[t] = W2[t];
    __syncthreads();

    const int row  = blockIdx.x * 4 + (threadIdx.x >> 6);
    if (row >= n) return;
    const int lane = threadIdx.x & 63;

    float tv = 0.f;
    if (lane < H1)
        tv = agg2[(size_t)row * H1 + lane] + c[(size_t)row * H1 + lane];

    const float dv = dis[row];
    float val = -INFINITY;
    if (lane < H2) {
        float s = 0.f;
        #pragma unroll
        for (int k = 0; k < H1; ++k) {
            float tk = __shfl(tv, k, 64);
            s += tk * w[k * H2 + lane];
        }
        val = dv * s + b2[lane];
    }
    float m = val;
    #pragma unroll
    for (int off = 32; off > 0; off >>= 1) m = fmaxf(m, __shfl_xor(m, off, 64));
    float ex = (lane < H2) ? __expf(val - m) : 0.f;
    #pragma unroll
    for (int off = 32; off > 0; off >>= 1) ex += __shfl_xor(ex, off, 64);
    if (lane < H2) out[(size_t)row * H2 + lane] = val - m - logf(ex);
}

// ---------------------------------------------------------------------------
extern "C" void kernel_launch(void* const* d_in, const int* in_sizes, int n_in,
                              void* d_out, int out_size, void* d_ws, size_t ws_size,
                              hipStream_t stream)
{
    const float* x   = (const float*)d_in[0];
    const void*  ei  = d_in[1];                 // int32 or int64 [2, E] — detected
    const float* W1  = (const float*)d_in[2];
    const float* b1  = (const float*)d_in[3];
    const float* W2  = (const float*)d_in[4];
    const float* b2  = (const float*)d_in[5];
    float*       out = (float*)d_out;

    // workspace layout (4-byte units); ~27.6 MB total, float4-aligned slabs.
    // REGION (E ints = 12.8MB) is time-multiplexed:
    //   CSR build:  packed
    //   pulls:      hs1 / c  (2 x N*16 floats = 12.8MB exactly)
    int*   base    = (int*)d_ws;
    int*   flag    = base;                                  // 16
    int*   deg     = base + 16;                             // N
    int*   row_end = deg + N_NODES;                         // N
    int*   bstart  = row_end + N_NODES;                     // 512 (NB+1 used)
    int*   cntoff  = bstart + 512;                          // B1*NB = 200192
    float* dis     = (float*)(cntoff + B1 * NB);            // N
    int*   csr     = (int*)(dis + N_NODES);                 // E
    int*   REGION  = csr + N_EDGES;                         // E
    int*   packed  = REGION;
    float* hs1     = (float*)REGION;                        // N*16
    float* c       = hs1 + (size_t)N_NODES * H1;            // N*16
    float* agg2    = hs1;                                   // hs1 dead after pull1

    detect_idx_kernel<<<1, 64, 0, stream>>>((const int*)ei, flag);

    hist_kernel<<<B1, 256, 0, stream>>>(ei, flag, cntoff);
    scanblk_kernel<<<(NB + 3) / 4, 256, 0, stream>>>(cntoff, bstart);
    scanb_kernel<<<1, 512, 0, stream>>>(bstart);
    scatter_bucket_kernel<<<B1, 256, 0, stream>>>(ei, flag, cntoff, bstart, packed);
    bucket_csr_kernel<<<NB, 512, 0, stream>>>(packed, bstart, deg, row_end, csr);

    gemm1_kernel<<<(N_NODES + GROWS - 1) / GROWS, 256, 0, stream>>>(
        x, W1, deg, hs1, dis, N_NODES);

    const int PB = (N_NODES * 4 + 255) / 256;
    pull16_kernel<1><<<PB, 256, 0, stream>>>(row_end, csr, hs1, dis, b1, c, N_NODES);
    pull16_kernel<0><<<PB, 256, 0, stream>>>(row_end, csr, c, dis, b1, agg2, N_NODES);

    epi_kernel<<<(N_NODES + 3) / 4, 256, 0, stream>>>(agg2, c, W2, b2, dis, out, N_NODES);
}